// Round 2
// baseline (287.392 us; speedup 1.0000x reference)
//
#include <hip/hip_runtime.h>

#define C_LEN 8192
#define Q_LEN 1024
#define DDIM  1024

typedef __attribute__((ext_vector_type(8))) short short8;
typedef __attribute__((ext_vector_type(4))) float f32x4;

// bf16 helpers (RNE)
static __device__ __forceinline__ unsigned short f2bf(float f){
  unsigned u = __float_as_uint(f);
  unsigned rounding = 0x7fffu + ((u >> 16) & 1u);
  return (unsigned short)((u + rounding) >> 16);
}
static __device__ __forceinline__ float bf2f(unsigned short b){
  return __uint_as_float(((unsigned)b) << 16);
}

static __device__ __forceinline__ void async_copy16(const void* g, void* l){
  __builtin_amdgcn_global_load_lds(
      (const __attribute__((address_space(1))) void*)g,
      (__attribute__((address_space(3))) void*)l, 16, 0, 0);
}

static __device__ __forceinline__ float waveRedSum(float v){
  #pragma unroll
  for(int o=32;o;o>>=1) v += __shfl_down(v,o);
  return v;
}
static __device__ __forceinline__ float waveRedMax(float v){
  #pragma unroll
  for(int o=32;o;o>>=1) v = fmaxf(v,__shfl_down(v,o));
  return v;
}

// One pass over H: Abf = bf16(H * w_qc), c_term = H@w_c + b_c,
// eb = exp(rowmax(H)), btot += exp(rowmax(H))
__global__ void prep_H(const float* __restrict__ H, const float* __restrict__ w_qc,
                       const float* __restrict__ w_c, const float* __restrict__ b_c,
                       unsigned short* __restrict__ Abf, float* __restrict__ c_term,
                       float* __restrict__ eb, float* __restrict__ btot){
  const int c = blockIdx.x, t = threadIdx.x;
  float4 h   = reinterpret_cast<const float4*>(H + (size_t)c*DDIM)[t];
  float4 wqc = reinterpret_cast<const float4*>(w_qc)[t];
  float4 wc  = reinterpret_cast<const float4*>(w_c)[t];
  float dot = h.x*wc.x + h.y*wc.y + h.z*wc.z + h.w*wc.w;
  float mx  = fmaxf(fmaxf(h.x,h.y), fmaxf(h.z,h.w));
  ushort4 o;
  o.x=f2bf(h.x*wqc.x); o.y=f2bf(h.y*wqc.y); o.z=f2bf(h.z*wqc.z); o.w=f2bf(h.w*wqc.w);
  reinterpret_cast<ushort4*>(Abf)[(size_t)c*256 + t] = o;
  __shared__ float sd[4], sm[4];
  int w=t>>6, l=t&63;
  dot = waveRedSum(dot); mx = waveRedMax(mx);
  if(l==0){ sd[w]=dot; sm[w]=mx; }
  __syncthreads();
  if(t==0){
    c_term[c] = sd[0]+sd[1]+sd[2]+sd[3] + b_c[0];
    float m = fmaxf(fmaxf(sm[0],sm[1]), fmaxf(sm[2],sm[3]));
    float e = __expf(m);           // |rowmax| <= ~5 -> exp safe without shift
    eb[c] = e;
    atomicAdd(btot, e);
  }
}

// One pass over U: Ubf = bf16(U), q_term = U@w_q + b_q
__global__ void prep_U(const float* __restrict__ U, const float* __restrict__ w_q,
                       const float* __restrict__ b_q, unsigned short* __restrict__ Ubf,
                       float* __restrict__ q_term){
  const int qr = blockIdx.x, t = threadIdx.x;
  float4 u  = reinterpret_cast<const float4*>(U + (size_t)qr*DDIM)[t];
  float4 wq = reinterpret_cast<const float4*>(w_q)[t];
  float dot = u.x*wq.x + u.y*wq.y + u.z*wq.z + u.w*wq.w;
  ushort4 o; o.x=f2bf(u.x); o.y=f2bf(u.y); o.z=f2bf(u.z); o.w=f2bf(u.w);
  reinterpret_cast<ushort4*>(Ubf)[(size_t)qr*256 + t] = o;
  __shared__ float sd[4];
  int w=t>>6, l=t&63;
  dot = waveRedSum(dot);
  if(l==0) sd[w]=dot;
  __syncthreads();
  if(t==0) q_term[qr] = sd[0]+sd[1]+sd[2]+sd[3] + b_q[0];
}

// Ut[d][q] = bf16(U[q][d]) via LDS 64x64 tiles
__global__ void transpose_U(const float* __restrict__ U, unsigned short* __restrict__ Ut){
  __shared__ float tile[64][65];
  const int t = threadIdx.x;
  const int q0 = blockIdx.y*64, d0 = blockIdx.x*64;
  #pragma unroll
  for(int i=0;i<16;i++){
    int idx = i*256 + t, r = idx>>6, col = idx&63;
    tile[r][col] = U[(size_t)(q0+r)*DDIM + d0 + col];
  }
  __syncthreads();
  #pragma unroll
  for(int i=0;i<16;i++){
    int idx = i*256 + t, r = idx>>6, col = idx&63;
    Ut[(size_t)(d0+r)*Q_LEN + q0 + col] = f2bf(tile[col][r]);
  }
}

// C[m][n] = sum_k A[m][k]*B[n][k]; bf16 in.
// FUSE_EXP=1: out = bf16(exp(C + rowAdd[m] + colAdd[n] + addC)), csum[n] += col sums
// FUSE_EXP=0: out = f32 C
// 128x128 tile, BK=32, 4 waves (2x2 of 64x64), 4x4 MFMA subtiles/wave.
// Staging via global_load_lds width=16 (m97 recipe): LDS layout MUST be
// unpadded [128][32] (wave-uniform base + lane*16 contiguous).
template<int FUSE_EXP>
__global__ __launch_bounds__(256)
void gemm_bt(const unsigned short* __restrict__ A, const unsigned short* __restrict__ B,
             void* __restrict__ Cout, int M, int N, int K,
             const float* __restrict__ rowAdd, const float* __restrict__ colAdd,
             const float* __restrict__ addC, float* __restrict__ csum){
  __shared__ unsigned short As[128][32];
  __shared__ unsigned short Bs[128][32];
  const int t = threadIdx.x;
  const int lane = t & 63, wave = t >> 6;
  const int wm = wave & 1, wn = wave >> 1;
  const int lr = lane & 15, quad = lane >> 4;
  const int bm = blockIdx.x * 128, bn = blockIdx.y * 128;
  const int srow = wave*32 + (lane>>2);   // staging row (chunk 0); +16 for chunk 1
  const int skcol = (lane&3)*8;           // staging k-offset in elements (16B)

  f32x4 acc[4][4];
  #pragma unroll
  for(int i=0;i<4;i++)
    #pragma unroll
    for(int j=0;j<4;j++) acc[i][j] = (f32x4){0.f,0.f,0.f,0.f};

  const unsigned short* gA = A + (size_t)(bm + srow)*K + skcol;
  const unsigned short* gB = B + (size_t)(bn + srow)*K + skcol;
  unsigned short* lA0 = &As[srow][skcol];
  unsigned short* lA1 = &As[srow+16][skcol];
  unsigned short* lB0 = &Bs[srow][skcol];
  unsigned short* lB1 = &Bs[srow+16][skcol];

  for(int k0=0;k0<K;k0+=32){
    async_copy16(gA,               lA0);
    async_copy16(gA + (size_t)16*K, lA1);
    async_copy16(gB,               lB0);
    async_copy16(gB + (size_t)16*K, lB1);
    gA += 32; gB += 32;
    __syncthreads();   // drains vmcnt -> LDS tiles complete
    short8 af[4], bfr[4];
    #pragma unroll
    for(int i=0;i<4;i++){
      af[i]  = *reinterpret_cast<const short8*>(&As[wm*64 + i*16 + lr][quad*8]);
      bfr[i] = *reinterpret_cast<const short8*>(&Bs[wn*64 + i*16 + lr][quad*8]);
    }
    #pragma unroll
    for(int i=0;i<4;i++)
      #pragma unroll
      for(int j=0;j<4;j++)
        acc[i][j] = __builtin_amdgcn_mfma_f32_16x16x32_bf16(af[i], bfr[j], acc[i][j], 0,0,0);
    __syncthreads();
  }

  const int col0 = bn + wn*64;
  if(FUSE_EXP){
    unsigned short* P = (unsigned short*)Cout;
    const float ac = addC[0];
    float cs[4];
    #pragma unroll
    for(int j=0;j<4;j++) cs[j] = 0.f;
    #pragma unroll
    for(int i=0;i<4;i++){
      int row0 = bm + wm*64 + i*16 + quad*4;
      float ra0 = rowAdd[row0], ra1 = rowAdd[row0+1], ra2 = rowAdd[row0+2], ra3 = rowAdd[row0+3];
      #pragma unroll
      for(int j=0;j<4;j++){
        int col = col0 + j*16 + lr;
        float cadd = colAdd[col] + ac;
        float e0 = __expf(acc[i][j][0] + ra0 + cadd);
        float e1 = __expf(acc[i][j][1] + ra1 + cadd);
        float e2 = __expf(acc[i][j][2] + ra2 + cadd);
        float e3 = __expf(acc[i][j][3] + ra3 + cadd);
        P[(size_t)(row0  )*N + col] = f2bf(e0);
        P[(size_t)(row0+1)*N + col] = f2bf(e1);
        P[(size_t)(row0+2)*N + col] = f2bf(e2);
        P[(size_t)(row0+3)*N + col] = f2bf(e3);
        cs[j] += e0+e1+e2+e3;
      }
    }
    #pragma unroll
    for(int j=0;j<4;j++){
      float v = cs[j];
      v += __shfl_xor(v, 16);
      v += __shfl_xor(v, 32);
      if(quad==0) atomicAdd(&csum[col0 + j*16 + lr], v);
    }
  } else {
    float* C = (float*)Cout;
    #pragma unroll
    for(int i=0;i<4;i++){
      int row0 = bm + wm*64 + i*16 + quad*4;
      #pragma unroll
      for(int j=0;j<4;j++){
        int col = col0 + j*16 + lr;
        #pragma unroll
        for(int r=0;r<4;r++)
          C[(size_t)(row0+r)*N + col] = acc[i][j][r];
      }
    }
  }
}

// fold 1/colsum into Ut (2MB instead of rescaling 16MB of P)
__global__ void scale_Ut(unsigned short* __restrict__ Ut, const float* __restrict__ csum){
  int idx = blockIdx.x*256 + threadIdx.x;  // 1M elements
  int q = idx & (Q_LEN-1);
  Ut[idx] = f2bf(bf2f(Ut[idx]) / csum[q]);
}

// Hrow[d] += sum_c eb[c]*H[c][d]  (unnormalized; bcast divides by btot)
__global__ void h_weighted(const float* __restrict__ H, const float* __restrict__ eb,
                           float* __restrict__ Hrow){
  int d  = blockIdx.x*256 + threadIdx.x;
  int c0 = blockIdx.y*256;
  float acc = 0.f;
  for(int c=c0;c<c0+256;c++)
    acc += eb[c] * H[(size_t)c*DDIM + d];
  atomicAdd(&Hrow[d], acc);
}

__global__ void bcast_H(const float* __restrict__ Hrow, const float* __restrict__ btot,
                        float4* __restrict__ out4){
  int gid = blockIdx.x*256 + threadIdx.x;   // 2M float4s = 8M floats
  int d4 = gid & 255;
  float inv = 1.f / btot[0];
  float4 v = reinterpret_cast<const float4*>(Hrow)[d4];
  v.x*=inv; v.y*=inv; v.z*=inv; v.w*=inv;
  out4[gid] = v;
}

extern "C" void kernel_launch(void* const* d_in, const int* in_sizes, int n_in,
                              void* d_out, int out_size, void* d_ws, size_t ws_size,
                              hipStream_t stream){
  const float* H    = (const float*)d_in[0];
  const float* U    = (const float*)d_in[1];
  const float* w_q  = (const float*)d_in[2];
  const float* b_q  = (const float*)d_in[3];
  const float* w_c  = (const float*)d_in[4];
  const float* b_c  = (const float*)d_in[5];
  const float* w_qc = (const float*)d_in[6];
  const float* b_qc = (const float*)d_in[7];
  float* out = (float*)d_out;
  char*  ws  = (char*)d_ws;

  unsigned short* P    = (unsigned short*)(ws);                // 16 MB
  unsigned short* Abf  = (unsigned short*)(ws + 16777216);     // 16 MB
  unsigned short* Ubf  = (unsigned short*)(ws + 33554432);     //  2 MB
  unsigned short* Utb  = (unsigned short*)(ws + 35651584);     //  2 MB
  char* stats = ws + 37748736;
  float* csum  = (float*)(stats);           // 4 KB  (zeroed)
  float* Hrow  = (float*)(stats + 4096);    // 4 KB  (zeroed)
  float* btot  = (float*)(stats + 8192);    // 4 B   (zeroed)
  float* cterm = (float*)(stats + 12288);   // 32 KB
  float* eb    = (float*)(stats + 45056);   // 32 KB
  float* qterm = (float*)(stats + 77824);   //  4 KB

  hipMemsetAsync(stats, 0, 12288, stream);  // csum, Hrow, btot

  prep_H<<<C_LEN, 256, 0, stream>>>(H, w_qc, w_c, b_c, Abf, cterm, eb, btot);
  prep_U<<<Q_LEN, 256, 0, stream>>>(U, w_q, b_q, Ubf, qterm);
  transpose_U<<<dim3(16,16), 256, 0, stream>>>(U, Utb);

  // S-free: GEMM1 writes P = bf16(exp(s)) and per-column sums directly
  gemm_bt<1><<<dim3(64,8), 256, 0, stream>>>(Abf, Ubf, (void*)P, C_LEN, Q_LEN, DDIM,
                                             cterm, qterm, b_qc, csum);

  scale_Ut<<<4096, 256, 0, stream>>>(Utb, csum);

  gemm_bt<0><<<dim3(64,8), 256, 0, stream>>>(P, Utb, (void*)out, C_LEN, DDIM, Q_LEN,
                                             nullptr, nullptr, nullptr, nullptr);

  h_weighted<<<dim3(4,32), 256, 0, stream>>>(H, eb, Hrow);
  bcast_H   <<<8192, 256, 0, stream>>>(Hrow, btot, (float4*)(out + (size_t)C_LEN*DDIM));
}

// Round 3
// 192.136 us; speedup vs baseline: 1.4958x; 1.4958x over previous
//
#include <hip/hip_runtime.h>

#define C_LEN 8192
#define Q_LEN 1024
#define DDIM  1024

typedef __attribute__((ext_vector_type(8))) short short8;
typedef __attribute__((ext_vector_type(4))) float f32x4;

// bf16 helpers (RNE)
static __device__ __forceinline__ unsigned short f2bf(float f){
  unsigned u = __float_as_uint(f);
  unsigned rounding = 0x7fffu + ((u >> 16) & 1u);
  return (unsigned short)((u + rounding) >> 16);
}
static __device__ __forceinline__ float bf2f(unsigned short b){
  return __uint_as_float(((unsigned)b) << 16);
}

static __device__ __forceinline__ void async_copy16(const void* g, void* l){
  __builtin_amdgcn_global_load_lds(
      (const __attribute__((address_space(1))) void*)g,
      (__attribute__((address_space(3))) void*)l, 16, 0, 0);
}

static __device__ __forceinline__ float waveRedSum(float v){
  #pragma unroll
  for(int o=32;o;o>>=1) v += __shfl_down(v,o);
  return v;
}
static __device__ __forceinline__ float waveRedMax(float v){
  #pragma unroll
  for(int o=32;o;o>>=1) v = fmaxf(v,__shfl_down(v,o));
  return v;
}

// One pass over H: Abf = bf16(H * w_qc), c_term = H@w_c + b_c, eb = exp(rowmax(H))
// NO single-address atomics (R2 post-mortem: 8192 serialized atomics = +100us)
__global__ void prep_H(const float* __restrict__ H, const float* __restrict__ w_qc,
                       const float* __restrict__ w_c, const float* __restrict__ b_c,
                       unsigned short* __restrict__ Abf, float* __restrict__ c_term,
                       float* __restrict__ eb){
  const int c = blockIdx.x, t = threadIdx.x;
  float4 h   = reinterpret_cast<const float4*>(H + (size_t)c*DDIM)[t];
  float4 wqc = reinterpret_cast<const float4*>(w_qc)[t];
  float4 wc  = reinterpret_cast<const float4*>(w_c)[t];
  float dot = h.x*wc.x + h.y*wc.y + h.z*wc.z + h.w*wc.w;
  float mx  = fmaxf(fmaxf(h.x,h.y), fmaxf(h.z,h.w));
  ushort4 o;
  o.x=f2bf(h.x*wqc.x); o.y=f2bf(h.y*wqc.y); o.z=f2bf(h.z*wqc.z); o.w=f2bf(h.w*wqc.w);
  reinterpret_cast<ushort4*>(Abf)[(size_t)c*256 + t] = o;
  __shared__ float sd[4], sm[4];
  int w=t>>6, l=t&63;
  dot = waveRedSum(dot); mx = waveRedMax(mx);
  if(l==0){ sd[w]=dot; sm[w]=mx; }
  __syncthreads();
  if(t==0){
    c_term[c] = sd[0]+sd[1]+sd[2]+sd[3] + b_c[0];
    float m = fmaxf(fmaxf(sm[0],sm[1]), fmaxf(sm[2],sm[3]));
    eb[c] = __expf(m);   // |rowmax| small -> exp safe without shift
  }
}

// btot = sum(eb) — one block, no atomics
__global__ void sum_eb(const float* __restrict__ eb, float* __restrict__ btot){
  __shared__ float red[16];
  int t = threadIdx.x, w = t>>6, l = t&63;
  float s = eb[t] + eb[t + 1024] + eb[t + 2048] + eb[t + 3072]
          + eb[t + 4096] + eb[t + 5120] + eb[t + 6144] + eb[t + 7168];
  s = waveRedSum(s);
  if(!l) red[w] = s;
  __syncthreads();
  if(t==0){ float tot=0.f; for(int i=0;i<16;i++) tot+=red[i]; btot[0]=tot; }
}

// One pass over U: Ubf = bf16(U), q_term = U@w_q + b_q
__global__ void prep_U(const float* __restrict__ U, const float* __restrict__ w_q,
                       const float* __restrict__ b_q, unsigned short* __restrict__ Ubf,
                       float* __restrict__ q_term){
  const int qr = blockIdx.x, t = threadIdx.x;
  float4 u  = reinterpret_cast<const float4*>(U + (size_t)qr*DDIM)[t];
  float4 wq = reinterpret_cast<const float4*>(w_q)[t];
  float dot = u.x*wq.x + u.y*wq.y + u.z*wq.z + u.w*wq.w;
  ushort4 o; o.x=f2bf(u.x); o.y=f2bf(u.y); o.z=f2bf(u.z); o.w=f2bf(u.w);
  reinterpret_cast<ushort4*>(Ubf)[(size_t)qr*256 + t] = o;
  __shared__ float sd[4];
  int w=t>>6, l=t&63;
  dot = waveRedSum(dot);
  if(l==0) sd[w]=dot;
  __syncthreads();
  if(t==0) q_term[qr] = sd[0]+sd[1]+sd[2]+sd[3] + b_q[0];
}

// Ut[d][q] = bf16(U[q][d]) via LDS 64x64 tiles
__global__ void transpose_U(const float* __restrict__ U, unsigned short* __restrict__ Ut){
  __shared__ float tile[64][65];
  const int t = threadIdx.x;
  const int q0 = blockIdx.y*64, d0 = blockIdx.x*64;
  #pragma unroll
  for(int i=0;i<16;i++){
    int idx = i*256 + t, r = idx>>6, col = idx&63;
    tile[r][col] = U[(size_t)(q0+r)*DDIM + d0 + col];
  }
  __syncthreads();
  #pragma unroll
  for(int i=0;i<16;i++){
    int idx = i*256 + t, r = idx>>6, col = idx&63;
    Ut[(size_t)(d0+r)*Q_LEN + q0 + col] = f2bf(tile[col][r]);
  }
}

// C[m][n] = sum_k A[m][k]*B[n][k]; bf16 in.
// FUSE_EXP=1: out = bf16(exp(C + rowAdd[m] + colAdd[n] + addC)), csum[n] += col sums
// FUSE_EXP=0: out = f32 C
// 128x128 tile, BK=32, 4 waves (2x2 of 64x64), 4x4 MFMA subtiles/wave.
// Staging via global_load_lds width=16 (m97 recipe, unpadded [128][32] LDS).
template<int FUSE_EXP>
__global__ __launch_bounds__(256)
void gemm_bt(const unsigned short* __restrict__ A, const unsigned short* __restrict__ B,
             void* __restrict__ Cout, int M, int N, int K,
             const float* __restrict__ rowAdd, const float* __restrict__ colAdd,
             const float* __restrict__ addC, float* __restrict__ csum){
  __shared__ unsigned short As[128][32];
  __shared__ unsigned short Bs[128][32];
  const int t = threadIdx.x;
  const int lane = t & 63, wave = t >> 6;
  const int wm = wave & 1, wn = wave >> 1;
  const int lr = lane & 15, quad = lane >> 4;
  const int bm = blockIdx.x * 128, bn = blockIdx.y * 128;
  const int srow = wave*32 + (lane>>2);
  const int skcol = (lane&3)*8;

  f32x4 acc[4][4];
  #pragma unroll
  for(int i=0;i<4;i++)
    #pragma unroll
    for(int j=0;j<4;j++) acc[i][j] = (f32x4){0.f,0.f,0.f,0.f};

  const unsigned short* gA = A + (size_t)(bm + srow)*K + skcol;
  const unsigned short* gB = B + (size_t)(bn + srow)*K + skcol;
  unsigned short* lA0 = &As[srow][skcol];
  unsigned short* lA1 = &As[srow+16][skcol];
  unsigned short* lB0 = &Bs[srow][skcol];
  unsigned short* lB1 = &Bs[srow+16][skcol];

  for(int k0=0;k0<K;k0+=32){
    async_copy16(gA,                lA0);
    async_copy16(gA + (size_t)16*K, lA1);
    async_copy16(gB,                lB0);
    async_copy16(gB + (size_t)16*K, lB1);
    gA += 32; gB += 32;
    __syncthreads();
    short8 af[4], bfr[4];
    #pragma unroll
    for(int i=0;i<4;i++){
      af[i]  = *reinterpret_cast<const short8*>(&As[wm*64 + i*16 + lr][quad*8]);
      bfr[i] = *reinterpret_cast<const short8*>(&Bs[wn*64 + i*16 + lr][quad*8]);
    }
    #pragma unroll
    for(int i=0;i<4;i++)
      #pragma unroll
      for(int j=0;j<4;j++)
        acc[i][j] = __builtin_amdgcn_mfma_f32_16x16x32_bf16(af[i], bfr[j], acc[i][j], 0,0,0);
    __syncthreads();
  }

  const int col0 = bn + wn*64;
  if(FUSE_EXP){
    unsigned short* P = (unsigned short*)Cout;
    const float ac = addC[0];
    float cs[4];
    #pragma unroll
    for(int j=0;j<4;j++) cs[j] = 0.f;
    #pragma unroll
    for(int i=0;i<4;i++){
      int row0 = bm + wm*64 + i*16 + quad*4;
      float ra0 = rowAdd[row0], ra1 = rowAdd[row0+1], ra2 = rowAdd[row0+2], ra3 = rowAdd[row0+3];
      #pragma unroll
      for(int j=0;j<4;j++){
        int col = col0 + j*16 + lr;
        float cadd = colAdd[col] + ac;
        float e0 = __expf(acc[i][j][0] + ra0 + cadd);
        float e1 = __expf(acc[i][j][1] + ra1 + cadd);
        float e2 = __expf(acc[i][j][2] + ra2 + cadd);
        float e3 = __expf(acc[i][j][3] + ra3 + cadd);
        P[(size_t)(row0  )*N + col] = f2bf(e0);
        P[(size_t)(row0+1)*N + col] = f2bf(e1);
        P[(size_t)(row0+2)*N + col] = f2bf(e2);
        P[(size_t)(row0+3)*N + col] = f2bf(e3);
        cs[j] += e0+e1+e2+e3;
      }
    }
    #pragma unroll
    for(int j=0;j<4;j++){
      float v = cs[j];
      v += __shfl_xor(v, 16);
      v += __shfl_xor(v, 32);
      if(quad==0) atomicAdd(&csum[col0 + j*16 + lr], v);   // 1024 addrs, 64 adds each: ok
    }
  } else {
    float* C = (float*)Cout;
    #pragma unroll
    for(int i=0;i<4;i++){
      int row0 = bm + wm*64 + i*16 + quad*4;
      #pragma unroll
      for(int j=0;j<4;j++){
        int col = col0 + j*16 + lr;
        #pragma unroll
        for(int r=0;r<4;r++)
          C[(size_t)(row0+r)*N + col] = acc[i][j][r];
      }
    }
  }
}

// fold 1/colsum into Ut (2MB instead of rescaling 16MB of P)
__global__ void scale_Ut(unsigned short* __restrict__ Ut, const float* __restrict__ csum){
  int idx = blockIdx.x*256 + threadIdx.x;
  int q = idx & (Q_LEN-1);
  Ut[idx] = f2bf(bf2f(Ut[idx]) / csum[q]);
}

// Hrow[d] += sum_c eb[c]*H[c][d]  (unnormalized; bcast divides by btot)
__global__ void h_weighted(const float* __restrict__ H, const float* __restrict__ eb,
                           float* __restrict__ Hrow){
  int d  = blockIdx.x*256 + threadIdx.x;
  int c0 = blockIdx.y*256;
  float acc = 0.f;
  for(int c=c0;c<c0+256;c++)
    acc += eb[c] * H[(size_t)c*DDIM + d];
  atomicAdd(&Hrow[d], acc);   // 1024 addrs, 32 adds each: ok
}

__global__ void bcast_H(const float* __restrict__ Hrow, const float* __restrict__ btot,
                        float4* __restrict__ out4){
  int gid = blockIdx.x*256 + threadIdx.x;
  int d4 = gid & 255;
  float inv = 1.f / btot[0];
  float4 v = reinterpret_cast<const float4*>(Hrow)[d4];
  v.x*=inv; v.y*=inv; v.z*=inv; v.w*=inv;
  out4[gid] = v;
}

extern "C" void kernel_launch(void* const* d_in, const int* in_sizes, int n_in,
                              void* d_out, int out_size, void* d_ws, size_t ws_size,
                              hipStream_t stream){
  const float* H    = (const float*)d_in[0];
  const float* U    = (const float*)d_in[1];
  const float* w_q  = (const float*)d_in[2];
  const float* b_q  = (const float*)d_in[3];
  const float* w_c  = (const float*)d_in[4];
  const float* b_c  = (const float*)d_in[5];
  const float* w_qc = (const float*)d_in[6];
  const float* b_qc = (const float*)d_in[7];
  float* out = (float*)d_out;
  char*  ws  = (char*)d_ws;

  unsigned short* P    = (unsigned short*)(ws);                // 16 MB
  unsigned short* Abf  = (unsigned short*)(ws + 16777216);     // 16 MB
  unsigned short* Ubf  = (unsigned short*)(ws + 33554432);     //  2 MB
  unsigned short* Utb  = (unsigned short*)(ws + 35651584);     //  2 MB
  char* stats = ws + 37748736;
  float* csum  = (float*)(stats);           // 4 KB  (zeroed)
  float* Hrow  = (float*)(stats + 4096);    // 4 KB  (zeroed)
  float* btot  = (float*)(stats + 8192);    // written by sum_eb
  float* cterm = (float*)(stats + 12288);   // 32 KB
  float* eb    = (float*)(stats + 45056);   // 32 KB
  float* qterm = (float*)(stats + 77824);   //  4 KB

  hipMemsetAsync(stats, 0, 8192, stream);  // csum, Hrow

  prep_H<<<C_LEN, 256, 0, stream>>>(H, w_qc, w_c, b_c, Abf, cterm, eb);
  prep_U<<<Q_LEN, 256, 0, stream>>>(U, w_q, b_q, Ubf, qterm);
  transpose_U<<<dim3(16,16), 256, 0, stream>>>(U, Utb);

  gemm_bt<1><<<dim3(64,8), 256, 0, stream>>>(Abf, Ubf, (void*)P, C_LEN, Q_LEN, DDIM,
                                             cterm, qterm, b_qc, csum);

  scale_Ut<<<4096, 256, 0, stream>>>(Utb, csum);

  gemm_bt<0><<<dim3(64,8), 256, 0, stream>>>(P, Utb, (void*)out, C_LEN, DDIM, Q_LEN,
                                             nullptr, nullptr, nullptr, nullptr);

  sum_eb    <<<1, 1024, 0, stream>>>(eb, btot);
  h_weighted<<<dim3(4,32), 256, 0, stream>>>(H, eb, Hrow);
  bcast_H   <<<8192, 256, 0, stream>>>(Hrow, btot, (float4*)(out + (size_t)C_LEN*DDIM));
}

// Round 4
// 176.974 us; speedup vs baseline: 1.6239x; 1.0857x over previous
//
#include <hip/hip_runtime.h>

#define C_LEN 8192
#define Q_LEN 1024
#define DDIM  1024

typedef __attribute__((ext_vector_type(8))) short short8;
typedef __attribute__((ext_vector_type(4))) float f32x4;

// bf16 helpers (RNE)
static __device__ __forceinline__ unsigned short f2bf(float f){
  unsigned u = __float_as_uint(f);
  unsigned rounding = 0x7fffu + ((u >> 16) & 1u);
  return (unsigned short)((u + rounding) >> 16);
}

static __device__ __forceinline__ void async_copy16(const void* g, void* l){
  __builtin_amdgcn_global_load_lds(
      (const __attribute__((address_space(1))) void*)g,
      (__attribute__((address_space(3))) void*)l, 16, 0, 0);
}

static __device__ __forceinline__ float waveRedSum(float v){
  #pragma unroll
  for(int o=32;o;o>>=1) v += __shfl_down(v,o);
  return v;
}
static __device__ __forceinline__ float waveRedMax(float v){
  #pragma unroll
  for(int o=32;o;o>>=1) v = fmaxf(v,__shfl_down(v,o));
  return v;
}

// One pass over H: Abf = bf16(H * w_qc), c_term = H@w_c + b_c, eb = exp(rowmax(H))
__global__ void prep_H(const float* __restrict__ H, const float* __restrict__ w_qc,
                       const float* __restrict__ w_c, const float* __restrict__ b_c,
                       unsigned short* __restrict__ Abf, float* __restrict__ c_term,
                       float* __restrict__ eb){
  const int c = blockIdx.x, t = threadIdx.x;
  float4 h   = reinterpret_cast<const float4*>(H + (size_t)c*DDIM)[t];
  float4 wqc = reinterpret_cast<const float4*>(w_qc)[t];
  float4 wc  = reinterpret_cast<const float4*>(w_c)[t];
  float dot = h.x*wc.x + h.y*wc.y + h.z*wc.z + h.w*wc.w;
  float mx  = fmaxf(fmaxf(h.x,h.y), fmaxf(h.z,h.w));
  ushort4 o;
  o.x=f2bf(h.x*wqc.x); o.y=f2bf(h.y*wqc.y); o.z=f2bf(h.z*wqc.z); o.w=f2bf(h.w*wqc.w);
  reinterpret_cast<ushort4*>(Abf)[(size_t)c*256 + t] = o;
  __shared__ float sd[4], sm[4];
  int w=t>>6, l=t&63;
  dot = waveRedSum(dot); mx = waveRedMax(mx);
  if(l==0){ sd[w]=dot; sm[w]=mx; }
  __syncthreads();
  if(t==0){
    c_term[c] = sd[0]+sd[1]+sd[2]+sd[3] + b_c[0];
    float m = fmaxf(fmaxf(sm[0],sm[1]), fmaxf(sm[2],sm[3]));
    eb[c] = __expf(m);
  }
}

// btot = sum(eb) — one block, no atomics
__global__ void sum_eb(const float* __restrict__ eb, float* __restrict__ btot){
  __shared__ float red[16];
  int t = threadIdx.x, w = t>>6, l = t&63;
  float s = eb[t] + eb[t + 1024] + eb[t + 2048] + eb[t + 3072]
          + eb[t + 4096] + eb[t + 5120] + eb[t + 6144] + eb[t + 7168];
  s = waveRedSum(s);
  if(!l) red[w] = s;
  __syncthreads();
  if(t==0){ float tot=0.f; for(int i=0;i<16;i++) tot+=red[i]; btot[0]=tot; }
}

// One pass over U: Ubf = bf16(U), q_term = U@w_q + b_q
__global__ void prep_U(const float* __restrict__ U, const float* __restrict__ w_q,
                       const float* __restrict__ b_q, unsigned short* __restrict__ Ubf,
                       float* __restrict__ q_term){
  const int qr = blockIdx.x, t = threadIdx.x;
  float4 u  = reinterpret_cast<const float4*>(U + (size_t)qr*DDIM)[t];
  float4 wq = reinterpret_cast<const float4*>(w_q)[t];
  float dot = u.x*wq.x + u.y*wq.y + u.z*wq.z + u.w*wq.w;
  ushort4 o; o.x=f2bf(u.x); o.y=f2bf(u.y); o.z=f2bf(u.z); o.w=f2bf(u.w);
  reinterpret_cast<ushort4*>(Ubf)[(size_t)qr*256 + t] = o;
  __shared__ float sd[4];
  int w=t>>6, l=t&63;
  dot = waveRedSum(dot);
  if(l==0) sd[w]=dot;
  __syncthreads();
  if(t==0) q_term[qr] = sd[0]+sd[1]+sd[2]+sd[3] + b_q[0];
}

// Ut[d][q] = bf16(U[q][d] / csum[q]) — transpose + normalization fold, one kernel
__global__ void transpose_scale_U(const float* __restrict__ U, const float* __restrict__ csum,
                                  unsigned short* __restrict__ Ut){
  __shared__ float tile[64][65];
  const int t = threadIdx.x;
  const int q0 = blockIdx.y*64, d0 = blockIdx.x*64;
  #pragma unroll
  for(int i=0;i<16;i++){
    int idx = i*256 + t, r = idx>>6, col = idx&63;
    tile[r][col] = U[(size_t)(q0+r)*DDIM + d0 + col];
  }
  // col index is t&63 for every i (256%64==0): one reciprocal per thread
  float inv = 1.f / csum[q0 + (t&63)];
  __syncthreads();
  #pragma unroll
  for(int i=0;i<16;i++){
    int idx = i*256 + t, r = idx>>6, col = idx&63;
    Ut[(size_t)(d0+r)*Q_LEN + q0 + col] = f2bf(tile[col][r] * inv);
  }
}

// C[m][n] = sum_k A[m][k]*B[n][k]; bf16 in.
// FUSE_EXP=1: out = bf16(exp(C + rowAdd[m] + colAdd[n] + addC)), csum[n] += col sums
// FUSE_EXP=0: out = f32 C
// 128x128 tile, BK=32, 4 waves, 4x4 MFMA subtiles/wave.
// DOUBLE-BUFFERED global_load_lds: one barrier per K-iter; prefetch k+1 into
// the other buffer right after the barrier so load latency overlaps MFMA.
template<int FUSE_EXP>
__global__ __launch_bounds__(256)
void gemm_bt(const unsigned short* __restrict__ A, const unsigned short* __restrict__ B,
             void* __restrict__ Cout, int M, int N, int K,
             const float* __restrict__ rowAdd, const float* __restrict__ colAdd,
             const float* __restrict__ addC, float* __restrict__ csum){
  __shared__ unsigned short As[2][128][32];
  __shared__ unsigned short Bs[2][128][32];
  const int t = threadIdx.x;
  const int lane = t & 63, wave = t >> 6;
  const int wm = wave & 1, wn = wave >> 1;
  const int lr = lane & 15, quad = lane >> 4;
  const int bm = blockIdx.x * 128, bn = blockIdx.y * 128;
  const int srow = wave*32 + (lane>>2);   // staging row (chunk 0); +16 for chunk 1
  const int skcol = (lane&3)*8;

  f32x4 acc[4][4];
  #pragma unroll
  for(int i=0;i<4;i++)
    #pragma unroll
    for(int j=0;j<4;j++) acc[i][j] = (f32x4){0.f,0.f,0.f,0.f};

  const unsigned short* gA = A + (size_t)(bm + srow)*K + skcol;
  const unsigned short* gB = B + (size_t)(bn + srow)*K + skcol;
  unsigned short* lA[2] = { &As[0][srow][skcol], &As[1][srow][skcol] };
  unsigned short* lB[2] = { &Bs[0][srow][skcol], &Bs[1][srow][skcol] };

  // prologue: stage k=0 into buffer 0
  async_copy16(gA,                lA[0]);
  async_copy16(gA + (size_t)16*K, lA[0] + 16*32);
  async_copy16(gB,                lB[0]);
  async_copy16(gB + (size_t)16*K, lB[0] + 16*32);
  gA += 32; gB += 32;

  const int ITERS = K >> 5;
  for(int k=0;k<ITERS;k++){
    const int cur = k & 1, nxt = cur ^ 1;
    __syncthreads();   // buf cur complete (vmcnt drain); prev reads of nxt done
    if(k+1 < ITERS){
      async_copy16(gA,                lA[nxt]);
      async_copy16(gA + (size_t)16*K, lA[nxt] + 16*32);
      async_copy16(gB,                lB[nxt]);
      async_copy16(gB + (size_t)16*K, lB[nxt] + 16*32);
      gA += 32; gB += 32;
    }
    short8 af[4], bfr[4];
    #pragma unroll
    for(int i=0;i<4;i++){
      af[i]  = *reinterpret_cast<const short8*>(&As[cur][wm*64 + i*16 + lr][quad*8]);
      bfr[i] = *reinterpret_cast<const short8*>(&Bs[cur][wn*64 + i*16 + lr][quad*8]);
    }
    #pragma unroll
    for(int i=0;i<4;i++)
      #pragma unroll
      for(int j=0;j<4;j++)
        acc[i][j] = __builtin_amdgcn_mfma_f32_16x16x32_bf16(af[i], bfr[j], acc[i][j], 0,0,0);
  }

  const int col0 = bn + wn*64;
  if(FUSE_EXP){
    unsigned short* P = (unsigned short*)Cout;
    const float ac = addC[0];
    float cs[4];
    #pragma unroll
    for(int j=0;j<4;j++) cs[j] = 0.f;
    #pragma unroll
    for(int i=0;i<4;i++){
      int row0 = bm + wm*64 + i*16 + quad*4;
      float ra0 = rowAdd[row0], ra1 = rowAdd[row0+1], ra2 = rowAdd[row0+2], ra3 = rowAdd[row0+3];
      #pragma unroll
      for(int j=0;j<4;j++){
        int col = col0 + j*16 + lr;
        float cadd = colAdd[col] + ac;
        float e0 = __expf(acc[i][j][0] + ra0 + cadd);
        float e1 = __expf(acc[i][j][1] + ra1 + cadd);
        float e2 = __expf(acc[i][j][2] + ra2 + cadd);
        float e3 = __expf(acc[i][j][3] + ra3 + cadd);
        P[(size_t)(row0  )*N + col] = f2bf(e0);
        P[(size_t)(row0+1)*N + col] = f2bf(e1);
        P[(size_t)(row0+2)*N + col] = f2bf(e2);
        P[(size_t)(row0+3)*N + col] = f2bf(e3);
        cs[j] += e0+e1+e2+e3;
      }
    }
    #pragma unroll
    for(int j=0;j<4;j++){
      float v = cs[j];
      v += __shfl_xor(v, 16);
      v += __shfl_xor(v, 32);
      if(quad==0) atomicAdd(&csum[col0 + j*16 + lr], v);
    }
  } else {
    float* C = (float*)Cout;
    #pragma unroll
    for(int i=0;i<4;i++){
      int row0 = bm + wm*64 + i*16 + quad*4;
      #pragma unroll
      for(int j=0;j<4;j++){
        int col = col0 + j*16 + lr;
        #pragma unroll
        for(int r=0;r<4;r++)
          C[(size_t)(row0+r)*N + col] = acc[i][j][r];
      }
    }
  }
}

// Hrow[d] += (1/btot) * sum_c eb[c]*H[c][d]
__global__ void h_weighted(const float* __restrict__ H, const float* __restrict__ eb,
                           const float* __restrict__ btot, float* __restrict__ Hrow){
  int d  = blockIdx.x*256 + threadIdx.x;
  int c0 = blockIdx.y*256;
  float acc = 0.f;
  for(int c=c0;c<c0+256;c++)
    acc += eb[c] * H[(size_t)c*DDIM + d];
  atomicAdd(&Hrow[d], acc * (1.f/btot[0]));
}

__global__ void bcast_H(const float* __restrict__ Hrow, float4* __restrict__ out4){
  int gid = blockIdx.x*256 + threadIdx.x;
  int d4 = gid & 255;
  out4[gid] = reinterpret_cast<const float4*>(Hrow)[d4];
}

extern "C" void kernel_launch(void* const* d_in, const int* in_sizes, int n_in,
                              void* d_out, int out_size, void* d_ws, size_t ws_size,
                              hipStream_t stream){
  const float* H    = (const float*)d_in[0];
  const float* U    = (const float*)d_in[1];
  const float* w_q  = (const float*)d_in[2];
  const float* b_q  = (const float*)d_in[3];
  const float* w_c  = (const float*)d_in[4];
  const float* b_c  = (const float*)d_in[5];
  const float* w_qc = (const float*)d_in[6];
  const float* b_qc = (const float*)d_in[7];
  float* out = (float*)d_out;
  char*  ws  = (char*)d_ws;

  unsigned short* P    = (unsigned short*)(ws);                // 16 MB
  unsigned short* Abf  = (unsigned short*)(ws + 16777216);     // 16 MB
  unsigned short* Ubf  = (unsigned short*)(ws + 33554432);     //  2 MB
  unsigned short* Utb  = (unsigned short*)(ws + 35651584);     //  2 MB
  char* stats = ws + 37748736;
  float* csum  = (float*)(stats);           // 4 KB  (zeroed)
  float* Hrow  = (float*)(stats + 4096);    // 4 KB  (zeroed)
  float* btot  = (float*)(stats + 8192);    // written by sum_eb
  float* cterm = (float*)(stats + 12288);   // 32 KB
  float* eb    = (float*)(stats + 45056);   // 32 KB
  float* qterm = (float*)(stats + 77824);   //  4 KB

  hipMemsetAsync(stats, 0, 8192, stream);  // csum, Hrow

  prep_H<<<C_LEN, 256, 0, stream>>>(H, w_qc, w_c, b_c, Abf, cterm, eb);
  prep_U<<<Q_LEN, 256, 0, stream>>>(U, w_q, b_q, Ubf, qterm);

  gemm_bt<1><<<dim3(64,8), 256, 0, stream>>>(Abf, Ubf, (void*)P, C_LEN, Q_LEN, DDIM,
                                             cterm, qterm, b_qc, csum);

  transpose_scale_U<<<dim3(16,16), 256, 0, stream>>>(U, csum, Utb);

  gemm_bt<0><<<dim3(64,8), 256, 0, stream>>>(P, Utb, (void*)out, C_LEN, DDIM, Q_LEN,
                                             nullptr, nullptr, nullptr, nullptr);

  sum_eb    <<<1, 1024, 0, stream>>>(eb, btot);
  h_weighted<<<dim3(4,32), 256, 0, stream>>>(H, eb, btot, Hrow);
  bcast_H   <<<8192, 256, 0, stream>>>(Hrow, (float4*)(out + (size_t)C_LEN*DDIM));
}

// Round 5
// 176.352 us; speedup vs baseline: 1.6296x; 1.0035x over previous
//
#include <hip/hip_runtime.h>

#define C_LEN 8192
#define Q_LEN 1024
#define DDIM  1024

typedef __attribute__((ext_vector_type(8))) short short8;
typedef __attribute__((ext_vector_type(4))) float f32x4;

// bf16 helpers (RNE)
static __device__ __forceinline__ unsigned short f2bf(float f){
  unsigned u = __float_as_uint(f);
  unsigned rounding = 0x7fffu + ((u >> 16) & 1u);
  return (unsigned short)((u + rounding) >> 16);
}

static __device__ __forceinline__ void async_copy16(const void* g, void* l){
  __builtin_amdgcn_global_load_lds(
      (const __attribute__((address_space(1))) void*)g,
      (__attribute__((address_space(3))) void*)l, 16, 0, 0);
}

static __device__ __forceinline__ float waveRedSum(float v){
  #pragma unroll
  for(int o=32;o;o>>=1) v += __shfl_down(v,o);
  return v;
}
static __device__ __forceinline__ float waveRedMax(float v){
  #pragma unroll
  for(int o=32;o;o>>=1) v = fmaxf(v,__shfl_down(v,o));
  return v;
}

// Merged prep: blocks [0,C_LEN) process H rows; blocks [C_LEN, C_LEN+Q_LEN) process U rows.
// H part: Abf = bf16(H*w_qc), cterm = H@w_c + b_c, eb = exp(rowmax(H))
// U part: Ubf = bf16(U), qterm = U@w_q + b_q, csum[qr] = 0 (kills the memset dispatch)
__global__ void prep_HU(const float* __restrict__ H, const float* __restrict__ U,
                        const float* __restrict__ w_qc, const float* __restrict__ w_c,
                        const float* __restrict__ b_c, const float* __restrict__ w_q,
                        const float* __restrict__ b_q,
                        unsigned short* __restrict__ Abf, float* __restrict__ cterm,
                        float* __restrict__ eb, unsigned short* __restrict__ Ubf,
                        float* __restrict__ qterm, float* __restrict__ csum){
  const int b = blockIdx.x, t = threadIdx.x;
  __shared__ float sd[4], sm[4];
  const int w = t>>6, l = t&63;
  if(b < C_LEN){
    float4 h   = reinterpret_cast<const float4*>(H + (size_t)b*DDIM)[t];
    float4 wqc = reinterpret_cast<const float4*>(w_qc)[t];
    float4 wc  = reinterpret_cast<const float4*>(w_c)[t];
    float dot = h.x*wc.x + h.y*wc.y + h.z*wc.z + h.w*wc.w;
    float mx  = fmaxf(fmaxf(h.x,h.y), fmaxf(h.z,h.w));
    ushort4 o;
    o.x=f2bf(h.x*wqc.x); o.y=f2bf(h.y*wqc.y); o.z=f2bf(h.z*wqc.z); o.w=f2bf(h.w*wqc.w);
    reinterpret_cast<ushort4*>(Abf)[(size_t)b*256 + t] = o;
    dot = waveRedSum(dot); mx = waveRedMax(mx);
    if(l==0){ sd[w]=dot; sm[w]=mx; }
    __syncthreads();
    if(t==0){
      cterm[b] = sd[0]+sd[1]+sd[2]+sd[3] + b_c[0];
      float m = fmaxf(fmaxf(sm[0],sm[1]), fmaxf(sm[2],sm[3]));
      eb[b] = __expf(m);   // |rowmax| small -> exp safe without shift
    }
  } else {
    const int qr = b - C_LEN;
    float4 u  = reinterpret_cast<const float4*>(U + (size_t)qr*DDIM)[t];
    float4 wq = reinterpret_cast<const float4*>(w_q)[t];
    float dot = u.x*wq.x + u.y*wq.y + u.z*wq.z + u.w*wq.w;
    ushort4 o; o.x=f2bf(u.x); o.y=f2bf(u.y); o.z=f2bf(u.z); o.w=f2bf(u.w);
    reinterpret_cast<ushort4*>(Ubf)[(size_t)qr*256 + t] = o;
    dot = waveRedSum(dot);
    if(l==0) sd[w]=dot;
    __syncthreads();
    if(t==0){
      qterm[qr] = sd[0]+sd[1]+sd[2]+sd[3] + b_q[0];
      csum[qr]  = 0.f;
    }
  }
}

// Hpart[cb][d] = sum over 256 c's of eb[c]*H[c][d]   (store-only, no atomics)
__global__ void h_weighted(const float* __restrict__ H, const float* __restrict__ eb,
                           float* __restrict__ Hpart){
  int d  = blockIdx.x*256 + threadIdx.x;
  int cb = blockIdx.y, c0 = cb*256;
  float acc = 0.f;
  for(int c=c0;c<c0+256;c++)
    acc += eb[c] * H[(size_t)c*DDIM + d];
  Hpart[cb*DDIM + d] = acc;
}

// Hrow[d] = (sum_cb Hpart[cb][d]) / sum(eb)
__global__ void combine_Hrow(const float* __restrict__ Hpart, const float* __restrict__ eb,
                             float* __restrict__ Hrow){
  __shared__ float red[4];
  int t = threadIdx.x, w = t>>6, l = t&63;
  float s = 0.f;
  for(int i=t;i<C_LEN;i+=256) s += eb[i];
  s = waveRedSum(s);
  if(!l) red[w] = s;
  __syncthreads();
  float btot = red[0]+red[1]+red[2]+red[3];
  int d = blockIdx.x*256 + t;
  float acc = 0.f;
  #pragma unroll
  for(int p=0;p<32;p++) acc += Hpart[p*DDIM + d];
  Hrow[d] = acc / btot;
}

// Ut[d][q] = bf16(U[q][d] / csum[q]) — transpose + normalization fold
__global__ void transpose_scale_U(const float* __restrict__ U, const float* __restrict__ csum,
                                  unsigned short* __restrict__ Ut){
  __shared__ float tile[64][65];
  const int t = threadIdx.x;
  const int q0 = blockIdx.y*64, d0 = blockIdx.x*64;
  #pragma unroll
  for(int i=0;i<16;i++){
    int idx = i*256 + t, r = idx>>6, col = idx&63;
    tile[r][col] = U[(size_t)(q0+r)*DDIM + d0 + col];
  }
  float inv = 1.f / csum[q0 + (t&63)];
  __syncthreads();
  #pragma unroll
  for(int i=0;i<16;i++){
    int idx = i*256 + t, r = idx>>6, col = idx&63;
    Ut[(size_t)(d0+r)*Q_LEN + q0 + col] = f2bf(tile[col][r] * inv);
  }
}

// C[m][n] = sum_k A[m][k]*B[n][k]; bf16 in. Grid must be (64,8) (M=8192, N=1024).
// FUSE_EXP=1: out = bf16(exp(C + rowAdd[m] + colAdd[n] + addC)), csum[n] += col sums
// FUSE_EXP=0: out = f32 C; additionally writes the H_toggler tile (rows = Hrow[bn..bn+128))
// 128x128 tile, BK=32, dbuf global_load_lds (one barrier/iter), 4x4 MFMA/wave.
// XCD swizzle: the 8 blocks sharing an A-slab (256KB) land on one XCD's L2.
template<int FUSE_EXP>
__global__ __launch_bounds__(256)
void gemm_bt(const unsigned short* __restrict__ A, const unsigned short* __restrict__ B,
             void* __restrict__ Cout, int M, int N, int K,
             const float* __restrict__ rowAdd, const float* __restrict__ colAdd,
             const float* __restrict__ addC, float* __restrict__ csum,
             const float* __restrict__ Hrow, float* __restrict__ outH){
  __shared__ unsigned short As[2][128][32];
  __shared__ unsigned short Bs[2][128][32];
  const int t = threadIdx.x;
  const int lane = t & 63, wave = t >> 6;
  const int wm = wave & 1, wn = wave >> 1;
  const int lr = lane & 15, quad = lane >> 4;
  // XCD-locality swizzle (assumes XCD = dispatch_linear % 8; speed-only heuristic)
  const int L = blockIdx.x + (blockIdx.y << 6);
  const int xcd = L & 7, r = L >> 3;
  const int by = r & 7, bx = ((r >> 3) << 3) | xcd;
  const int bm = bx * 128, bn = by * 128;
  const int srow = wave*32 + (lane>>2);
  const int skcol = (lane&3)*8;

  f32x4 acc[4][4];
  #pragma unroll
  for(int i=0;i<4;i++)
    #pragma unroll
    for(int j=0;j<4;j++) acc[i][j] = (f32x4){0.f,0.f,0.f,0.f};

  const unsigned short* gA = A + (size_t)(bm + srow)*K + skcol;
  const unsigned short* gB = B + (size_t)(bn + srow)*K + skcol;
  unsigned short* lA[2] = { &As[0][srow][skcol], &As[1][srow][skcol] };
  unsigned short* lB[2] = { &Bs[0][srow][skcol], &Bs[1][srow][skcol] };

  async_copy16(gA,                lA[0]);
  async_copy16(gA + (size_t)16*K, lA[0] + 16*32);
  async_copy16(gB,                lB[0]);
  async_copy16(gB + (size_t)16*K, lB[0] + 16*32);
  gA += 32; gB += 32;

  const int ITERS = K >> 5;
  for(int k=0;k<ITERS;k++){
    const int cur = k & 1, nxt = cur ^ 1;
    __syncthreads();
    if(k+1 < ITERS){
      async_copy16(gA,                lA[nxt]);
      async_copy16(gA + (size_t)16*K, lA[nxt] + 16*32);
      async_copy16(gB,                lB[nxt]);
      async_copy16(gB + (size_t)16*K, lB[nxt] + 16*32);
      gA += 32; gB += 32;
    }
    short8 af[4], bfr[4];
    #pragma unroll
    for(int i=0;i<4;i++){
      af[i]  = *reinterpret_cast<const short8*>(&As[cur][wm*64 + i*16 + lr][quad*8]);
      bfr[i] = *reinterpret_cast<const short8*>(&Bs[cur][wn*64 + i*16 + lr][quad*8]);
    }
    #pragma unroll
    for(int i=0;i<4;i++)
      #pragma unroll
      for(int j=0;j<4;j++)
        acc[i][j] = __builtin_amdgcn_mfma_f32_16x16x32_bf16(af[i], bfr[j], acc[i][j], 0,0,0);
  }

  const int col0 = bn + wn*64;
  if(FUSE_EXP){
    unsigned short* P = (unsigned short*)Cout;
    const float ac = addC[0];
    float cs[4];
    #pragma unroll
    for(int j=0;j<4;j++) cs[j] = 0.f;
    #pragma unroll
    for(int i=0;i<4;i++){
      int row0 = bm + wm*64 + i*16 + quad*4;
      float ra0 = rowAdd[row0], ra1 = rowAdd[row0+1], ra2 = rowAdd[row0+2], ra3 = rowAdd[row0+3];
      #pragma unroll
      for(int j=0;j<4;j++){
        int col = col0 + j*16 + lr;
        float cadd = colAdd[col] + ac;
        float e0 = __expf(acc[i][j][0] + ra0 + cadd);
        float e1 = __expf(acc[i][j][1] + ra1 + cadd);
        float e2 = __expf(acc[i][j][2] + ra2 + cadd);
        float e3 = __expf(acc[i][j][3] + ra3 + cadd);
        P[(size_t)(row0  )*N + col] = f2bf(e0);
        P[(size_t)(row0+1)*N + col] = f2bf(e1);
        P[(size_t)(row0+2)*N + col] = f2bf(e2);
        P[(size_t)(row0+3)*N + col] = f2bf(e3);
        cs[j] += e0+e1+e2+e3;
      }
    }
    #pragma unroll
    for(int j=0;j<4;j++){
      float v = cs[j];
      v += __shfl_xor(v, 16);
      v += __shfl_xor(v, 32);
      if(quad==0) atomicAdd(&csum[col0 + j*16 + lr], v);
    }
  } else {
    float* C = (float*)Cout;
    #pragma unroll
    for(int i=0;i<4;i++){
      int row0 = bm + wm*64 + i*16 + quad*4;
      #pragma unroll
      for(int j=0;j<4;j++){
        int col = col0 + j*16 + lr;
        #pragma unroll
        for(int r=0;r<4;r++)
          C[(size_t)(row0+r)*N + col] = acc[i][j][r];
      }
    }
    // fused H_toggler tile: every row of [bm..bm+128) x [bn..bn+128) = Hrow[bn+..]
    float4 hv = reinterpret_cast<const float4*>(Hrow + bn)[t & 31];
    #pragma unroll
    for(int rr = t>>5; rr < 128; rr += 8)
      reinterpret_cast<float4*>(outH + (size_t)(bm+rr)*DDIM + bn)[t & 31] = hv;
  }
}

extern "C" void kernel_launch(void* const* d_in, const int* in_sizes, int n_in,
                              void* d_out, int out_size, void* d_ws, size_t ws_size,
                              hipStream_t stream){
  const float* H    = (const float*)d_in[0];
  const float* U    = (const float*)d_in[1];
  const float* w_q  = (const float*)d_in[2];
  const float* b_q  = (const float*)d_in[3];
  const float* w_c  = (const float*)d_in[4];
  const float* b_c  = (const float*)d_in[5];
  const float* w_qc = (const float*)d_in[6];
  const float* b_qc = (const float*)d_in[7];
  float* out = (float*)d_out;
  char*  ws  = (char*)d_ws;

  unsigned short* P    = (unsigned short*)(ws);                // 16 MB
  unsigned short* Abf  = (unsigned short*)(ws + 16777216);     // 16 MB
  unsigned short* Ubf  = (unsigned short*)(ws + 33554432);     //  2 MB
  unsigned short* Utb  = (unsigned short*)(ws + 35651584);     //  2 MB
  char* stats = ws + 37748736;
  float* csum  = (float*)(stats);           //  4 KB (zeroed by prep_HU)
  float* Hrow  = (float*)(stats + 4096);    //  4 KB
  float* cterm = (float*)(stats + 12288);   // 32 KB
  float* eb    = (float*)(stats + 45056);   // 32 KB
  float* qterm = (float*)(stats + 77824);   //  4 KB
  float* Hpart = (float*)(stats + 81920);   // 128 KB

  prep_HU<<<C_LEN + Q_LEN, 256, 0, stream>>>(H, U, w_qc, w_c, b_c, w_q, b_q,
                                             Abf, cterm, eb, Ubf, qterm, csum);

  h_weighted  <<<dim3(4,32), 256, 0, stream>>>(H, eb, Hpart);
  combine_Hrow<<<4, 256, 0, stream>>>(Hpart, eb, Hrow);

  gemm_bt<1><<<dim3(64,8), 256, 0, stream>>>(Abf, Ubf, (void*)P, C_LEN, Q_LEN, DDIM,
                                             cterm, qterm, b_qc, csum, nullptr, nullptr);

  transpose_scale_U<<<dim3(16,16), 256, 0, stream>>>(U, csum, Utb);

  gemm_bt<0><<<dim3(64,8), 256, 0, stream>>>(P, Utb, (void*)out, C_LEN, DDIM, Q_LEN,
                                             nullptr, nullptr, nullptr, nullptr,
                                             Hrow, out + (size_t)C_LEN*DDIM);
}